// Round 7
// baseline (1529.285 us; speedup 1.0000x reference)
//
#include <hip/hip_runtime.h>
#include <math.h>

#define BB 2
#define NN 1024
#define DD 128
#define HH 8
#define NL 8
#define RR 4
#define DHID 256
#define TWO_R 8
#define MM (BB*NN)
#define TB 2048   // bias table resolution over d in [0,20]

typedef __attribute__((ext_vector_type(8))) short short8;
typedef __attribute__((ext_vector_type(4))) float f32x4;

__device__ __forceinline__ float gelu_erf(float x) {
    return 0.5f * x * (1.0f + erff(x * 0.70710678118654752f));
}
// f32 -> bf16 round-to-nearest-even
__device__ __forceinline__ ushort f2b(float f) {
    union { float f; unsigned u; } v; v.f = f;
    return (ushort)((v.u + 0x7FFFu + ((v.u >> 16) & 1u)) >> 16);
}
__device__ __forceinline__ float b2f(ushort u) {
    union { unsigned u; float f; } v; v.u = ((unsigned)u) << 16;
    return v.f;
}
__device__ __forceinline__ unsigned pk2(float a, float b) {
    return ((unsigned)f2b(b) << 16) | (unsigned)f2b(a);
}

// ---------------------------------------------------------------------------
// Merged f32->bf16 weight conversion (4 segments, one elem/thread)
// ---------------------------------------------------------------------------
__global__ __launch_bounds__(256) void cvt4_kernel(
    const float* __restrict__ s0, int n0, const float* __restrict__ s1, int n1,
    const float* __restrict__ s2, int n2, const float* __restrict__ s3, int n3,
    ushort* __restrict__ d0, ushort* __restrict__ d1,
    ushort* __restrict__ d2, ushort* __restrict__ d3) {
    int t = blockIdx.x * 256 + threadIdx.x;
    if (t < n0) { d0[t] = f2b(s0[t]); return; } t -= n0;
    if (t < n1) { d1[t] = f2b(s1[t]); return; } t -= n1;
    if (t < n2) { d2[t] = f2b(s2[t]); return; } t -= n2;
    if (t < n3) { d3[t] = f2b(s3[t]); }
}

// masks -> bf16: fmask = attn+local, amask = attn
__global__ __launch_bounds__(256) void maskprep_kernel(
    const float* __restrict__ am, const float* __restrict__ lm,
    ushort* __restrict__ fmask, ushort* __restrict__ amask) {
    int t = blockIdx.x * 256 + threadIdx.x;
    if (t >= BB * NN * NN) return;
    float a = am[t];
    amask[t] = f2b(a);
    fmask[t] = f2b(a + lm[t]);
}

// ---------------------------------------------------------------------------
// Bias table: tab[l][et][idx][h] = gelu(LN([rbf(d_idx), emb_l[et]]) @ W_l + b_l)
// d_idx = idx * 20/(TB-1). Exact reference pipeline, evaluated 64K times once.
// ---------------------------------------------------------------------------
__global__ __launch_bounds__(256) void table_kernel(
    const float* __restrict__ de_ln_g, const float* __restrict__ de_ln_b,
    const float* __restrict__ de_w, const float* __restrict__ de_b,
    const float* __restrict__ edge_emb, const float* __restrict__ mu,
    const float* __restrict__ sigma, float* __restrict__ tab) {
    int t = blockIdx.x * 256 + threadIdx.x;
    if (t >= NL * 4 * TB) return;
    int idx = t & (TB - 1);
    int et = (t >> 11) & 3;
    int l = t >> 13;
    float d = idx * (20.0f / (float)(TB - 1));
    float f[8];
#pragma unroll
    for (int r = 0; r < RR; ++r) {
        float u = (d - mu[r]) / sigma[r];
        f[r] = expf(-u * u);
    }
#pragma unroll
    for (int r = 0; r < RR; ++r) f[4 + r] = edge_emb[(l * 4 + et) * RR + r];
    float m = 0.f;
#pragma unroll
    for (int r = 0; r < 8; ++r) m += f[r];
    m *= 0.125f;
    float v = 0.f;
#pragma unroll
    for (int r = 0; r < 8; ++r) { float dd = f[r] - m; v += dd * dd; }
    v *= 0.125f;
    float inv = rsqrtf(v + 1e-5f);
    float fn[8];
#pragma unroll
    for (int r = 0; r < 8; ++r)
        fn[r] = (f[r] - m) * inv * de_ln_g[l * 8 + r] + de_ln_b[l * 8 + r];
#pragma unroll
    for (int h = 0; h < HH; ++h) {
        float z = de_b[l * 8 + h];
#pragma unroll
        for (int r = 0; r < 8; ++r) z += de_w[(l * 8 + h) * 8 + r] * fn[r];
        tab[(size_t)t * 8 + h] = gelu_erf(z);
    }
}

// ---------------------------------------------------------------------------
// MFMA GEMM: C[m,n] = epi( sum_k A[m,k]*W[n,k] ), acc f32.
// Tile 64x64, 4 waves (2x2 of 32x32), K staged fully in LDS.
// AMODE: 0 = A bf16 [M][K]; 1 = A f32 [M][128] with fused LayerNorm;
//        2 = A = f2b(opart[0] + opart[1]) (f32 partials [2][MM][128])
// FLAGS: 1=+bias[n], 2=gelu, 4=resid+ls, 8=bf16 out
// ---------------------------------------------------------------------------
#define GF_BIAS 1
#define GF_GELU 2
#define GF_RESID 4
#define GF_OUTBF 8

template <int AMODE, int FLAGS, int KDIM>
__global__ __launch_bounds__(256) void gemm_mfma(
    const void* __restrict__ Ain, const ushort* __restrict__ W,
    const float* __restrict__ bias, const float* __restrict__ ls,
    const float* __restrict__ resid, const float* __restrict__ lng,
    const float* __restrict__ lnb, void* __restrict__ out, int Nd) {
    __shared__ ushort As[64][KDIM + 8];
    __shared__ ushort Ws[64][KDIM + 8];
    int tid = threadIdx.x;
    int bm = blockIdx.x, bn = blockIdx.y;
    if (AMODE == 1) {
        // fused LayerNorm over K=128: 4 threads/row, 32 elems each
        int r = tid >> 2, c = tid & 3;
        const float* xr = (const float*)Ain + (size_t)(bm * 64 + r) * 128 + c * 32;
        float v[32];
        float s = 0.f, ss = 0.f;
#pragma unroll
        for (int k = 0; k < 8; ++k) {
            float4 f = ((const float4*)xr)[k];
            v[4 * k] = f.x; v[4 * k + 1] = f.y; v[4 * k + 2] = f.z; v[4 * k + 3] = f.w;
            s += f.x + f.y + f.z + f.w;
            ss += f.x * f.x + f.y * f.y + f.z * f.z + f.w * f.w;
        }
        s += __shfl_xor(s, 1, 64);  s += __shfl_xor(s, 2, 64);
        ss += __shfl_xor(ss, 1, 64); ss += __shfl_xor(ss, 2, 64);
        float mean = s * (1.f / 128.f);
        float var = ss * (1.f / 128.f) - mean * mean;
        float inv = rsqrtf(var + 1e-5f);
        unsigned* dst = (unsigned*)&As[r][c * 32];
#pragma unroll
        for (int k = 0; k < 16; ++k) {
            int col = c * 32 + 2 * k;
            float a0 = (v[2 * k] - mean) * inv * lng[col] + lnb[col];
            float a1 = (v[2 * k + 1] - mean) * inv * lng[col + 1] + lnb[col + 1];
            dst[k] = pk2(a0, a1);
        }
    } else if (AMODE == 2) {
        const float* Apart = (const float*)Ain;
        for (int v = tid; v < 64 * 32; v += 256) {
            int r = v >> 5, c = v & 31;
            size_t off = (size_t)(bm * 64 + r) * 128 + c * 4;
            float4 s0 = *(const float4*)(Apart + off);
            float4 s1 = *(const float4*)(Apart + (size_t)MM * 128 + off);
            unsigned* dst = (unsigned*)&As[r][c * 4];
            dst[0] = pk2(s0.x + s1.x, s0.y + s1.y);
            dst[1] = pk2(s0.z + s1.z, s0.w + s1.w);
        }
    } else {
        const ushort* A = (const ushort*)Ain;
        for (int v = tid; v < 64 * KDIM / 8; v += 256) {
            int r = v / (KDIM / 8), c = v % (KDIM / 8);
            *(short8*)&As[r][c * 8] =
                *(const short8*)(A + (size_t)(bm * 64 + r) * KDIM + c * 8);
        }
    }
    for (int v = tid; v < 64 * KDIM / 8; v += 256) {
        int r = v / (KDIM / 8), c = v % (KDIM / 8);
        *(short8*)&Ws[r][c * 8] =
            *(const short8*)(W + (size_t)(bn * 64 + r) * KDIM + c * 8);
    }
    __syncthreads();
    int wv = tid >> 6, l = tid & 63;
    int wm = (wv >> 1) * 32, wn = (wv & 1) * 32;
    int lr = l & 15, lk = (l >> 4) * 8;
    f32x4 acc[2][2] = {};
#pragma unroll
    for (int k0 = 0; k0 < KDIM; k0 += 32) {
        short8 af[2], bf[2];
        af[0] = *(const short8*)&As[wm + lr][k0 + lk];
        af[1] = *(const short8*)&As[wm + 16 + lr][k0 + lk];
        bf[0] = *(const short8*)&Ws[wn + lr][k0 + lk];
        bf[1] = *(const short8*)&Ws[wn + 16 + lr][k0 + lk];
#pragma unroll
        for (int mf = 0; mf < 2; ++mf)
#pragma unroll
            for (int nf = 0; nf < 2; ++nf)
                acc[mf][nf] = __builtin_amdgcn_mfma_f32_16x16x32_bf16(
                    af[mf], bf[nf], acc[mf][nf], 0, 0, 0);
    }
#pragma unroll
    for (int mf = 0; mf < 2; ++mf)
#pragma unroll
        for (int nf = 0; nf < 2; ++nf) {
            int n = bn * 64 + wn + nf * 16 + lr;
            float bv = (FLAGS & GF_BIAS) ? bias[n] : 0.f;
            float lv = (FLAGS & GF_RESID) ? ls[n] : 0.f;
#pragma unroll
            for (int q = 0; q < 4; ++q) {
                int m = bm * 64 + wm + mf * 16 + (l >> 4) * 4 + q;
                float c = acc[mf][nf][q];
                c += bv;
                if (FLAGS & GF_GELU) c = gelu_erf(c);
                size_t idx = (size_t)m * Nd + n;
                if (FLAGS & GF_RESID) c = resid[idx] + lv * c;
                if (FLAGS & GF_OUTBF) ((ushort*)out)[idx] = f2b(c);
                else ((float*)out)[idx] = c;
            }
        }
}

// ---------------------------------------------------------------------------
// Score via MFMA, ALL 8 HEADS per block (dist/et/mask read once per point):
// a[b,h,i,j] = 0.25*QK^T + mask(bf16) + lerp(tab[et,d])[h] -> bf16.
// Block: 16i x 64j tile; wave w owns heads 2w,2w+1 (8 MFMA/wave).
// Per-point epilogue: one dist/et/mask load, float2 table gathers (h pair).
// grid: (jt=16, it=64, b=2)
// ---------------------------------------------------------------------------
__global__ __launch_bounds__(256) void score_mfma(
    const ushort* __restrict__ qkv, const float* __restrict__ dist,
    const int* __restrict__ edge_type, const float* __restrict__ tabl,
    const ushort* __restrict__ mask, ushort* __restrict__ a) {
    int tid = threadIdx.x, wv = tid >> 6, l = tid & 63;
    int jt = blockIdx.x, it = blockIdx.y, b = blockIdx.z;
    int i0 = it * 16, j0 = jt * 64;
    int h0 = wv * 2;
    int lr = l & 15, kk = (l >> 4) * 8;
    short8 zero = {0, 0, 0, 0, 0, 0, 0, 0};
    bool lo = kk < 16;
    short8 af[2];
    short8 bf[2][4];
    f32x4 acc[2][4] = {};
#pragma unroll
    for (int hh = 0; hh < 2; ++hh) {
        af[hh] = zero;
        if (lo)
            af[hh] = *(const short8*)(qkv + (size_t)(b * NN + i0 + lr) * 384 +
                                      (h0 + hh) * 16 + kk);
#pragma unroll
        for (int nf = 0; nf < 4; ++nf) {
            bf[hh][nf] = zero;
            if (lo)
                bf[hh][nf] = *(const short8*)(qkv +
                                              (size_t)(b * NN + j0 + nf * 16 + lr) * 384 +
                                              128 + (h0 + hh) * 16 + kk);
        }
    }
#pragma unroll
    for (int hh = 0; hh < 2; ++hh)
#pragma unroll
        for (int nf = 0; nf < 4; ++nf)
            acc[hh][nf] = __builtin_amdgcn_mfma_f32_16x16x32_bf16(
                af[hh], bf[hh][nf], acc[hh][nf], 0, 0, 0);
#pragma unroll
    for (int nf = 0; nf < 4; ++nf)
#pragma unroll
        for (int q = 0; q < 4; ++q) {
            int i = i0 + (l >> 4) * 4 + q;
            int j = j0 + nf * 16 + lr;
            size_t mi = ((size_t)b * NN + i) * NN + j;
            float d = dist[mi];
            int et = edge_type[mi];
            float msk = b2f(mask[mi]);
            float u = d * ((float)(TB - 1) / 20.0f);
            int t0i = (int)u;
            t0i = t0i < 0 ? 0 : (t0i > TB - 2 ? TB - 2 : t0i);
            float fr = u - (float)t0i;
            const float* tp = tabl + ((size_t)et * TB + t0i) * 8 + h0;
            float2 lo2 = *(const float2*)tp;
            float2 hi2 = *(const float2*)(tp + 8);
            float bv0 = lo2.x + fr * (hi2.x - lo2.x);
            float bv1 = lo2.y + fr * (hi2.y - lo2.y);
            size_t ai0 = ((size_t)(b * HH + h0) * NN + i) * NN + j;
            a[ai0] = f2b(acc[0][nf][q] * 0.25f + msk + bv0);
            a[ai0 + (size_t)NN * NN] = f2b(acc[1][nf][q] * 0.25f + msk + bv1);
        }
}

// ---------------------------------------------------------------------------
// Talking-heads: premix -> softmax(j, no-max: scores bounded <~15, masked
// entries -1e4 -> exp underflows to 0 exactly) -> postmix, IN-PLACE on bf16 a.
// Block per (b,i); thread owns j = 4*tid..4*tid+3 for all heads; 1 barrier.
// ---------------------------------------------------------------------------
__global__ __launch_bounds__(256) void mixsm_kernel(
    ushort* __restrict__ a, const float* __restrict__ pre,
    const float* __restrict__ post) {
    __shared__ float red[8][4];
    int bi = blockIdx.x;
    int b = bi >> 10, i = bi & 1023;
    int tid = threadIdx.x, wave = tid >> 6, lane = tid & 63;
    float vals[8][4];
#pragma unroll
    for (int h = 0; h < HH; ++h) {
        uint2 w = *(const uint2*)(a + ((size_t)(b * HH + h) * NN + i) * NN + 4 * tid);
        vals[h][0] = b2f((ushort)(w.x & 0xFFFF));
        vals[h][1] = b2f((ushort)(w.x >> 16));
        vals[h][2] = b2f((ushort)(w.y & 0xFFFF));
        vals[h][3] = b2f((ushort)(w.y >> 16));
    }
    float e[8][4];
#pragma unroll
    for (int g = 0; g < HH; ++g) {
        float pr[8];
#pragma unroll
        for (int h = 0; h < 8; ++h) pr[h] = pre[g * 8 + h];
        float z = 0.f;
#pragma unroll
        for (int q = 0; q < 4; ++q) {
            float m = 0.f;
#pragma unroll
            for (int h = 0; h < 8; ++h) m += pr[h] * vals[h][q];
            e[g][q] = __expf(m);
            z += e[g][q];
        }
#pragma unroll
        for (int o = 32; o; o >>= 1) z += __shfl_xor(z, o, 64);
        if (lane == 0) red[g][wave] = z;
    }
    __syncthreads();
#pragma unroll
    for (int g = 0; g < HH; ++g) {
        float rz = 1.f / (red[g][0] + red[g][1] + red[g][2] + red[g][3]);
#pragma unroll
        for (int q = 0; q < 4; ++q) e[g][q] *= rz;
    }
#pragma unroll
    for (int g = 0; g < HH; ++g) {
        float po[8];
#pragma unroll
        for (int h = 0; h < 8; ++h) po[h] = post[g * 8 + h];
        float o4[4];
#pragma unroll
        for (int q = 0; q < 4; ++q) {
            float s = 0.f;
#pragma unroll
            for (int h = 0; h < 8; ++h) s += po[h] * e[h][q];
            o4[q] = s;
        }
        uint2 w;
        w.x = pk2(o4[0], o4[1]);
        w.y = pk2(o4[2], o4[3]);
        *(uint2*)(a + ((size_t)(b * HH + g) * NN + i) * NN + 4 * tid) = w;
    }
}

// ---------------------------------------------------------------------------
// AV via MFMA, split-j into 2 f32 partials (summed in proj GEMM staging).
// Block: 4 waves x 16i = 64i, j-range 512. grid x = it(16)*2+js(2) = 32, y=16.
// 512 blocks -> 2 blocks/CU (8 waves/CU). Two independent MFMA acc chains
// (even/odd ks) double per-wave ILP; exact same summands.
// ---------------------------------------------------------------------------
__global__ __launch_bounds__(256) void av_mfma(
    const ushort* __restrict__ p, const ushort* __restrict__ qkv,
    float* __restrict__ opart) {
    __shared__ ushort Vs[16][520];
    int bx = blockIdx.x;
    int it = bx >> 1, js = bx & 1;
    int bh = blockIdx.y;
    int b = bh >> 3, h = bh & 7;
    int tid = threadIdx.x, wv = tid >> 6, l = tid & 63;
    int i0 = it * 64 + wv * 16;
    int j0 = js * 512;
    for (int jl = tid; jl < 512; jl += 256) {
        const ushort* src = qkv + (size_t)(b * NN + j0 + jl) * 384 + 256 + h * 16;
        short8 v0 = *(const short8*)src;
        short8 v1 = *(const short8*)(src + 8);
#pragma unroll
        for (int d = 0; d < 8; ++d) Vs[d][jl] = (ushort)v0[d];
#pragma unroll
        for (int d = 0; d < 8; ++d) Vs[8 + d][jl] = (ushort)v1[d];
    }
    __syncthreads();
    int lr = l & 15, lk = (l >> 4) * 8;
    const ushort* prow = p + ((size_t)bh * NN + i0 + lr) * NN + j0;
    f32x4 acc0 = {}, acc1 = {};
#pragma unroll
    for (int ks = 0; ks < 16; ks += 2) {
        int jb0 = ks * 32 + lk;
        int jb1 = (ks + 1) * 32 + lk;
        short8 bv0 = *(const short8*)&Vs[lr][jb0];
        short8 bv1 = *(const short8*)&Vs[lr][jb1];
        short8 a0 = *(const short8*)(prow + jb0);
        short8 a1 = *(const short8*)(prow + jb1);
        acc0 = __builtin_amdgcn_mfma_f32_16x16x32_bf16(a0, bv0, acc0, 0, 0, 0);
        acc1 = __builtin_amdgcn_mfma_f32_16x16x32_bf16(a1, bv1, acc1, 0, 0, 0);
    }
    f32x4 acc = acc0 + acc1;
#pragma unroll
    for (int q = 0; q < 4; ++q) {
        int m = i0 + (l >> 4) * 4 + q;
        opart[((size_t)js * MM + b * NN + m) * DD + h * 16 + lr] = acc[q];
    }
}

// ---------------------------------------------------------------------------
extern "C" void kernel_launch(void* const* d_in, const int* in_sizes, int n_in,
                              void* d_out, int out_size, void* d_ws, size_t ws_size,
                              hipStream_t stream) {
    const float* x         = (const float*)d_in[0];
    const float* dist      = (const float*)d_in[1];
    const float* attn_mask = (const float*)d_in[2];
    const float* local_mask= (const float*)d_in[3];
    const int*   edge_type = (const int*)d_in[4];
    const float* ln_g      = (const float*)d_in[5];
    const float* ln_b      = (const float*)d_in[6];
    const float* qkv_w     = (const float*)d_in[7];
    const float* proj_w    = (const float*)d_in[8];
    const float* proj_b    = (const float*)d_in[9];
    const float* th_pre    = (const float*)d_in[10];
    const float* th_post   = (const float*)d_in[11];
    const float* ls        = (const float*)d_in[12];
    const float* fc1_w     = (const float*)d_in[13];
    const float* fc1_b     = (const float*)d_in[14];
    const float* fc2_w     = (const float*)d_in[15];
    const float* fc2_b     = (const float*)d_in[16];
    const float* de_ln_g   = (const float*)d_in[17];
    const float* de_ln_b   = (const float*)d_in[18];
    const float* de_w      = (const float*)d_in[19];
    const float* de_b      = (const float*)d_in[20];
    const float* edge_emb  = (const float*)d_in[21];
    const float* rbf_mu    = (const float*)d_in[22];
    const float* rbf_sigma = (const float*)d_in[23];

    char* pws = (char*)d_ws;
    auto alloc = [&](size_t bytes) {
        char* r = pws;
        pws += (bytes + 255) & ~(size_t)255;
        return (void*)r;
    };
    const int NWQ = NL * 2 * 3 * DD * DD;
    const int NWP = NL * 2 * DD * DD;
    const int NW1 = NL * DHID * DD;
    const int NW2 = NL * DD * DHID;
    ushort* wq    = (ushort*)alloc((size_t)NWQ * 2);
    ushort* wp    = (ushort*)alloc((size_t)NWP * 2);
    ushort* w1    = (ushort*)alloc((size_t)NW1 * 2);
    ushort* w2    = (ushort*)alloc((size_t)NW2 * 2);
    ushort* abuf  = (ushort*)alloc((size_t)BB * HH * NN * NN * 2);  // 32 MB
    ushort* fmask = (ushort*)alloc((size_t)BB * NN * NN * 2);       // 4 MB
    ushort* amask = (ushort*)alloc((size_t)BB * NN * NN * 2);       // 4 MB
    float*  xbuf  = (float*)alloc((size_t)MM * DD * 4);
    ushort* qkvb  = (ushort*)alloc((size_t)MM * 3 * DD * 2);
    ushort* h1    = (ushort*)alloc((size_t)MM * DHID * 2);
    float*  opart = (float*)alloc((size_t)2 * MM * DD * 4);         // 2 MB
    float*  tab   = (float*)alloc((size_t)NL * 4 * TB * 8 * 4);     // 2 MB

    {
        int ntot = NWQ + NWP + NW1 + NW2;
        cvt4_kernel<<<(ntot + 255) / 256, 256, 0, stream>>>(
            qkv_w, NWQ, proj_w, NWP, fc1_w, NW1, fc2_w, NW2, wq, wp, w1, w2);
        maskprep_kernel<<<(BB * NN * NN + 255) / 256, 256, 0, stream>>>(
            attn_mask, local_mask, fmask, amask);
        table_kernel<<<(NL * 4 * TB + 255) / 256, 256, 0, stream>>>(
            de_ln_g, de_ln_b, de_w, de_b, edge_emb, rbf_mu, rbf_sigma, tab);
    }

    hipMemcpyAsync(xbuf, x, (size_t)MM * DD * 4, hipMemcpyDeviceToDevice, stream);

    for (int l = 0; l < NL; ++l) {
        const float* tabl = tab + (size_t)l * 4 * TB * 8;
        for (int inst = 0; inst < 2; ++inst) {
            gemm_mfma<1, GF_OUTBF, 128><<<dim3(MM / 64, 384 / 64), 256, 0, stream>>>(
                xbuf, wq + (size_t)(l * 2 + inst) * 3 * DD * DD,
                nullptr, nullptr, nullptr,
                ln_g + (l * 3 + inst) * DD, ln_b + (l * 3 + inst) * DD, qkvb, 384);
            score_mfma<<<dim3(NN / 64, NN / 16, BB), 256, 0, stream>>>(
                qkvb, dist, edge_type, tabl, inst == 0 ? fmask : amask, abuf);
            mixsm_kernel<<<BB * NN, 256, 0, stream>>>(
                abuf, th_pre + (l * 2 + inst) * HH * HH,
                th_post + (l * 2 + inst) * HH * HH);
            av_mfma<<<dim3(32, BB * HH), 256, 0, stream>>>(abuf, qkvb, opart);
            gemm_mfma<2, GF_BIAS | GF_RESID, 128>
                <<<dim3(MM / 64, DD / 64), 256, 0, stream>>>(
                opart, wp + (size_t)(l * 2 + inst) * DD * DD,
                proj_b + (l * 2 + inst) * DD, ls + (l * 3 + inst) * DD,
                xbuf, nullptr, nullptr, xbuf, DD);
        }

        gemm_mfma<1, GF_BIAS | GF_GELU | GF_OUTBF, 128>
            <<<dim3(MM / 64, DHID / 64), 256, 0, stream>>>(
            xbuf, w1 + (size_t)l * DHID * DD, fc1_b + l * DHID,
            nullptr, nullptr, ln_g + (l * 3 + 2) * DD, ln_b + (l * 3 + 2) * DD,
            h1, DHID);
        gemm_mfma<0, GF_BIAS | GF_RESID, 256>
            <<<dim3(MM / 64, DD / 64), 256, 0, stream>>>(
            h1, w2 + (size_t)l * DD * DHID, fc2_b + l * DD,
            ls + (l * 3 + 2) * DD, xbuf, nullptr, nullptr, xbuf, DD);
    }

    hipMemcpyAsync(d_out, xbuf, (size_t)MM * DD * 4, hipMemcpyDeviceToDevice, stream);
}

// Round 10
// 1425.936 us; speedup vs baseline: 1.0725x; 1.0725x over previous
//
#include <hip/hip_runtime.h>
#include <math.h>

#define BB 2
#define NN 1024
#define DD 128
#define HH 8
#define NL 8
#define RR 4
#define DHID 256
#define TWO_R 8
#define MM (BB*NN)
#define TB 2048   // bias table resolution over d in [0,20]

typedef __attribute__((ext_vector_type(8))) short short8;
typedef __attribute__((ext_vector_type(4))) float f32x4;

__device__ __forceinline__ float gelu_erf(float x) {
    return 0.5f * x * (1.0f + erff(x * 0.70710678118654752f));
}
// f32 -> bf16 round-to-nearest-even
__device__ __forceinline__ ushort f2b(float f) {
    union { float f; unsigned u; } v; v.f = f;
    return (ushort)((v.u + 0x7FFFu + ((v.u >> 16) & 1u)) >> 16);
}
__device__ __forceinline__ float b2f(ushort u) {
    union { unsigned u; float f; } v; v.u = ((unsigned)u) << 16;
    return v.f;
}
__device__ __forceinline__ unsigned pk2(float a, float b) {
    return ((unsigned)f2b(b) << 16) | (unsigned)f2b(a);
}

// ---------------------------------------------------------------------------
// Merged f32->bf16 weight conversion (4 segments, one elem/thread)
// ---------------------------------------------------------------------------
__global__ __launch_bounds__(256) void cvt4_kernel(
    const float* __restrict__ s0, int n0, const float* __restrict__ s1, int n1,
    const float* __restrict__ s2, int n2, const float* __restrict__ s3, int n3,
    ushort* __restrict__ d0, ushort* __restrict__ d1,
    ushort* __restrict__ d2, ushort* __restrict__ d3) {
    int t = blockIdx.x * 256 + threadIdx.x;
    if (t < n0) { d0[t] = f2b(s0[t]); return; } t -= n0;
    if (t < n1) { d1[t] = f2b(s1[t]); return; } t -= n1;
    if (t < n2) { d2[t] = f2b(s2[t]); return; } t -= n2;
    if (t < n3) { d3[t] = f2b(s3[t]); }
}

// masks -> bf16: fmask = attn+local, amask = attn
__global__ __launch_bounds__(256) void maskprep_kernel(
    const float* __restrict__ am, const float* __restrict__ lm,
    ushort* __restrict__ fmask, ushort* __restrict__ amask) {
    int t = blockIdx.x * 256 + threadIdx.x;
    if (t >= BB * NN * NN) return;
    float a = am[t];
    amask[t] = f2b(a);
    fmask[t] = f2b(a + lm[t]);
}

// ---------------------------------------------------------------------------
// Bias table: tab[l][et][idx][h] = gelu(LN([rbf(d_idx), emb_l[et]]) @ W_l + b_l)
// d_idx = idx * 20/(TB-1). Exact reference pipeline, evaluated 64K times once.
// ---------------------------------------------------------------------------
__global__ __launch_bounds__(256) void table_kernel(
    const float* __restrict__ de_ln_g, const float* __restrict__ de_ln_b,
    const float* __restrict__ de_w, const float* __restrict__ de_b,
    const float* __restrict__ edge_emb, const float* __restrict__ mu,
    const float* __restrict__ sigma, float* __restrict__ tab) {
    int t = blockIdx.x * 256 + threadIdx.x;
    if (t >= NL * 4 * TB) return;
    int idx = t & (TB - 1);
    int et = (t >> 11) & 3;
    int l = t >> 13;
    float d = idx * (20.0f / (float)(TB - 1));
    float f[8];
#pragma unroll
    for (int r = 0; r < RR; ++r) {
        float u = (d - mu[r]) / sigma[r];
        f[r] = expf(-u * u);
    }
#pragma unroll
    for (int r = 0; r < RR; ++r) f[4 + r] = edge_emb[(l * 4 + et) * RR + r];
    float m = 0.f;
#pragma unroll
    for (int r = 0; r < 8; ++r) m += f[r];
    m *= 0.125f;
    float v = 0.f;
#pragma unroll
    for (int r = 0; r < 8; ++r) { float dd = f[r] - m; v += dd * dd; }
    v *= 0.125f;
    float inv = rsqrtf(v + 1e-5f);
    float fn[8];
#pragma unroll
    for (int r = 0; r < 8; ++r)
        fn[r] = (f[r] - m) * inv * de_ln_g[l * 8 + r] + de_ln_b[l * 8 + r];
#pragma unroll
    for (int h = 0; h < HH; ++h) {
        float z = de_b[l * 8 + h];
#pragma unroll
        for (int r = 0; r < 8; ++r) z += de_w[(l * 8 + h) * 8 + r] * fn[r];
        tab[(size_t)t * 8 + h] = gelu_erf(z);
    }
}

// ---------------------------------------------------------------------------
// MFMA GEMM: C[m,n] = epi( sum_k A[m,k]*W[n,k] ), acc f32.
// Tile 64x64, 4 waves (2x2 of 32x32), K staged fully in LDS.
// AMODE: 0 = A bf16 [M][K]; 1 = A f32 [M][128] with fused LayerNorm;
//        2 = A = f2b(opart[0] + opart[1]) (f32 partials [2][MM][128])
// FLAGS: 1=+bias[n], 2=gelu, 4=resid+ls, 8=bf16 out
// ---------------------------------------------------------------------------
#define GF_BIAS 1
#define GF_GELU 2
#define GF_RESID 4
#define GF_OUTBF 8

template <int AMODE, int FLAGS, int KDIM>
__global__ __launch_bounds__(256) void gemm_mfma(
    const void* __restrict__ Ain, const ushort* __restrict__ W,
    const float* __restrict__ bias, const float* __restrict__ ls,
    const float* __restrict__ resid, const float* __restrict__ lng,
    const float* __restrict__ lnb, void* __restrict__ out, int Nd) {
    __shared__ ushort As[64][KDIM + 8];
    __shared__ ushort Ws[64][KDIM + 8];
    int tid = threadIdx.x;
    int bm = blockIdx.x, bn = blockIdx.y;
    if (AMODE == 1) {
        // fused LayerNorm over K=128: 4 threads/row, 32 elems each
        int r = tid >> 2, c = tid & 3;
        const float* xr = (const float*)Ain + (size_t)(bm * 64 + r) * 128 + c * 32;
        float v[32];
        float s = 0.f, ss = 0.f;
#pragma unroll
        for (int k = 0; k < 8; ++k) {
            float4 f = ((const float4*)xr)[k];
            v[4 * k] = f.x; v[4 * k + 1] = f.y; v[4 * k + 2] = f.z; v[4 * k + 3] = f.w;
            s += f.x + f.y + f.z + f.w;
            ss += f.x * f.x + f.y * f.y + f.z * f.z + f.w * f.w;
        }
        s += __shfl_xor(s, 1, 64);  s += __shfl_xor(s, 2, 64);
        ss += __shfl_xor(ss, 1, 64); ss += __shfl_xor(ss, 2, 64);
        float mean = s * (1.f / 128.f);
        float var = ss * (1.f / 128.f) - mean * mean;
        float inv = rsqrtf(var + 1e-5f);
        unsigned* dst = (unsigned*)&As[r][c * 32];
#pragma unroll
        for (int k = 0; k < 16; ++k) {
            int col = c * 32 + 2 * k;
            float a0 = (v[2 * k] - mean) * inv * lng[col] + lnb[col];
            float a1 = (v[2 * k + 1] - mean) * inv * lng[col + 1] + lnb[col + 1];
            dst[k] = pk2(a0, a1);
        }
    } else if (AMODE == 2) {
        const float* Apart = (const float*)Ain;
        for (int v = tid; v < 64 * 32; v += 256) {
            int r = v >> 5, c = v & 31;
            size_t off = (size_t)(bm * 64 + r) * 128 + c * 4;
            float4 s0 = *(const float4*)(Apart + off);
            float4 s1 = *(const float4*)(Apart + (size_t)MM * 128 + off);
            unsigned* dst = (unsigned*)&As[r][c * 4];
            dst[0] = pk2(s0.x + s1.x, s0.y + s1.y);
            dst[1] = pk2(s0.z + s1.z, s0.w + s1.w);
        }
    } else {
        const ushort* A = (const ushort*)Ain;
        for (int v = tid; v < 64 * KDIM / 8; v += 256) {
            int r = v / (KDIM / 8), c = v % (KDIM / 8);
            *(short8*)&As[r][c * 8] =
                *(const short8*)(A + (size_t)(bm * 64 + r) * KDIM + c * 8);
        }
    }
    for (int v = tid; v < 64 * KDIM / 8; v += 256) {
        int r = v / (KDIM / 8), c = v % (KDIM / 8);
        *(short8*)&Ws[r][c * 8] =
            *(const short8*)(W + (size_t)(bn * 64 + r) * KDIM + c * 8);
    }
    __syncthreads();
    int wv = tid >> 6, l = tid & 63;
    int wm = (wv >> 1) * 32, wn = (wv & 1) * 32;
    int lr = l & 15, lk = (l >> 4) * 8;
    f32x4 acc[2][2] = {};
#pragma unroll
    for (int k0 = 0; k0 < KDIM; k0 += 32) {
        short8 af[2], bf[2];
        af[0] = *(const short8*)&As[wm + lr][k0 + lk];
        af[1] = *(const short8*)&As[wm + 16 + lr][k0 + lk];
        bf[0] = *(const short8*)&Ws[wn + lr][k0 + lk];
        bf[1] = *(const short8*)&Ws[wn + 16 + lr][k0 + lk];
#pragma unroll
        for (int mf = 0; mf < 2; ++mf)
#pragma unroll
            for (int nf = 0; nf < 2; ++nf)
                acc[mf][nf] = __builtin_amdgcn_mfma_f32_16x16x32_bf16(
                    af[mf], bf[nf], acc[mf][nf], 0, 0, 0);
    }
#pragma unroll
    for (int mf = 0; mf < 2; ++mf)
#pragma unroll
        for (int nf = 0; nf < 2; ++nf) {
            int n = bn * 64 + wn + nf * 16 + lr;
            float bv = (FLAGS & GF_BIAS) ? bias[n] : 0.f;
            float lv = (FLAGS & GF_RESID) ? ls[n] : 0.f;
#pragma unroll
            for (int q = 0; q < 4; ++q) {
                int m = bm * 64 + wm + mf * 16 + (l >> 4) * 4 + q;
                float c = acc[mf][nf][q];
                c += bv;
                if (FLAGS & GF_GELU) c = gelu_erf(c);
                size_t idx = (size_t)m * Nd + n;
                if (FLAGS & GF_RESID) c = resid[idx] + lv * c;
                if (FLAGS & GF_OUTBF) ((ushort*)out)[idx] = f2b(c);
                else ((float*)out)[idx] = c;
            }
        }
}

// ---------------------------------------------------------------------------
// Score via MFMA, restructured (R7): cooperative LDS staging of per-point
// (mask+bias) computed ONCE per block (was 4x redundant across waves, 80
// scattered loads/thread), then QK^T, then epilogue reads LDS, then fully
// coalesced b128 writeout (was 32 scattered 2B stores/thread).
// a[b,h,i,j] = 0.25*QK^T + (mask + lerp(tab[et,d])[h]) -> bf16.
// Block: 16i x 64j tile, all 8 heads; wave w owns heads 2w,2w+1.
// grid: (jt=16, it=64, b=2)
// ---------------------------------------------------------------------------
__global__ __launch_bounds__(256) void score_mfma(
    const ushort* __restrict__ qkv, const float* __restrict__ dist,
    const int* __restrict__ edge_type, const float* __restrict__ tabl,
    const ushort* __restrict__ mask, ushort* __restrict__ a) {
    __shared__ unsigned bm2[4][1024];   // (mask+bias) bf16x2 per head-pair; pt=il*64+jl (16KB)
    __shared__ ushort st[8][16][72];    // score tile staging, padded rows (18KB)
    int tid = threadIdx.x, wv = tid >> 6, l = tid & 63;
    int jt = blockIdx.x, it = blockIdx.y, b = blockIdx.z;
    int i0 = it * 16, j0 = jt * 64;
    // ---- phase 1: per-point mask+bias -> LDS (4 consecutive points/thread) ----
    {
        int p0 = tid * 4;
        int il = p0 >> 6, jl = p0 & 63;
        size_t mi = ((size_t)(b * NN + i0 + il)) * NN + j0 + jl;
        float4 d4 = *(const float4*)(dist + mi);
        int4 e4 = *(const int4*)(edge_type + mi);
        uint2 mk = *(const uint2*)(mask + mi);
        float mk4[4] = { b2f((ushort)(mk.x & 0xFFFF)), b2f((ushort)(mk.x >> 16)),
                         b2f((ushort)(mk.y & 0xFFFF)), b2f((ushort)(mk.y >> 16)) };
        float dv[4] = { d4.x, d4.y, d4.z, d4.w };
        int ev[4] = { e4.x, e4.y, e4.z, e4.w };
        unsigned o[4][4];
#pragma unroll
        for (int p = 0; p < 4; ++p) {
            float u = dv[p] * ((float)(TB - 1) / 20.0f);
            int t0i = (int)u;
            t0i = t0i < 0 ? 0 : (t0i > TB - 2 ? TB - 2 : t0i);
            float fr = u - (float)t0i;
            const float* tp = tabl + ((size_t)ev[p] * TB + t0i) * 8;
            float4 lo0 = *(const float4*)tp;
            float4 lo1 = *(const float4*)(tp + 4);
            float4 hi0 = *(const float4*)(tp + 8);
            float4 hi1 = *(const float4*)(tp + 12);
            float m = mk4[p];
            o[p][0] = pk2(m + lo0.x + fr * (hi0.x - lo0.x),
                          m + lo0.y + fr * (hi0.y - lo0.y));
            o[p][1] = pk2(m + lo0.z + fr * (hi0.z - lo0.z),
                          m + lo0.w + fr * (hi0.w - lo0.w));
            o[p][2] = pk2(m + lo1.x + fr * (hi1.x - lo1.x),
                          m + lo1.y + fr * (hi1.y - lo1.y));
            o[p][3] = pk2(m + lo1.z + fr * (hi1.z - lo1.z),
                          m + lo1.w + fr * (hi1.w - lo1.w));
        }
#pragma unroll
        for (int hp = 0; hp < 4; ++hp) {
            uint4 w4;
            w4.x = o[0][hp]; w4.y = o[1][hp]; w4.z = o[2][hp]; w4.w = o[3][hp];
            *reinterpret_cast<uint4*>(&bm2[hp][p0]) = w4;
        }
    }
    // ---- phase 2: QK^T for head pair (h0, h0+1) ----
    int h0 = wv * 2;
    int lr = l & 15, kk = (l >> 4) * 8;
    short8 zero = {0, 0, 0, 0, 0, 0, 0, 0};
    bool lo = kk < 16;
    short8 af[2];
    short8 bf[2][4];
    f32x4 acc[2][4] = {};
#pragma unroll
    for (int hh = 0; hh < 2; ++hh) {
        af[hh] = zero;
        if (lo)
            af[hh] = *(const short8*)(qkv + (size_t)(b * NN + i0 + lr) * 384 +
                                      (h0 + hh) * 16 + kk);
#pragma unroll
        for (int nf = 0; nf < 4; ++nf) {
            bf[hh][nf] = zero;
            if (lo)
                bf[hh][nf] = *(const short8*)(qkv +
                                              (size_t)(b * NN + j0 + nf * 16 + lr) * 384 +
                                              128 + (h0 + hh) * 16 + kk);
        }
    }
#pragma unroll
    for (int hh = 0; hh < 2; ++hh)
#pragma unroll
        for (int nf = 0; nf < 4; ++nf)
            acc[hh][nf] = __builtin_amdgcn_mfma_f32_16x16x32_bf16(
                af[hh], bf[hh][nf], acc[hh][nf], 0, 0, 0);
    __syncthreads();   // bm2 ready
    // ---- phase 3: add bias+mask, stage score tile in LDS ----
#pragma unroll
    for (int nf = 0; nf < 4; ++nf)
#pragma unroll
        for (int q = 0; q < 4; ++q) {
            int il = (l >> 4) * 4 + q;
            int jl = nf * 16 + lr;
            unsigned bmv = bm2[wv][il * 64 + jl];
            st[h0][il][jl]     = f2b(acc[0][nf][q] * 0.25f + b2f((ushort)(bmv & 0xFFFF)));
            st[h0 + 1][il][jl] = f2b(acc[1][nf][q] * 0.25f + b2f((ushort)(bmv >> 16)));
        }
    __syncthreads();
    // ---- phase 4: coalesced writeout: thread t -> (h,il) half-row of 32 j ----
    {
        int row = tid >> 1;            // 0..127 over (h, il)
        int h = row >> 4, il = row & 15;
        int jl = (tid & 1) * 32;
        const ushort* src = &st[h][il][jl];
        ushort* dst = a + ((size_t)(b * HH + h) * NN + i0 + il) * NN + j0 + jl;
        *reinterpret_cast<uint4*>(dst)      = *reinterpret_cast<const uint4*>(src);
        *reinterpret_cast<uint4*>(dst + 8)  = *reinterpret_cast<const uint4*>(src + 8);
        *reinterpret_cast<uint4*>(dst + 16) = *reinterpret_cast<const uint4*>(src + 16);
        *reinterpret_cast<uint4*>(dst + 24) = *reinterpret_cast<const uint4*>(src + 24);
    }
}

// ---------------------------------------------------------------------------
// Talking-heads: premix -> softmax(j, no-max: scores bounded <~15, masked
// entries -1e4 -> exp underflows to 0 exactly) -> postmix, IN-PLACE on bf16 a.
// Block per (b,i); thread owns j = 4*tid..4*tid+3 for all heads; 1 barrier.
// ---------------------------------------------------------------------------
__global__ __launch_bounds__(256) void mixsm_kernel(
    ushort* __restrict__ a, const float* __restrict__ pre,
    const float* __restrict__ post) {
    __shared__ float red[8][4];
    int bi = blockIdx.x;
    int b = bi >> 10, i = bi & 1023;
    int tid = threadIdx.x, wave = tid >> 6, lane = tid & 63;
    float vals[8][4];
#pragma unroll
    for (int h = 0; h < HH; ++h) {
        uint2 w = *(const uint2*)(a + ((size_t)(b * HH + h) * NN + i) * NN + 4 * tid);
        vals[h][0] = b2f((ushort)(w.x & 0xFFFF));
        vals[h][1] = b2f((ushort)(w.x >> 16));
        vals[h][2] = b2f((ushort)(w.y & 0xFFFF));
        vals[h][3] = b2f((ushort)(w.y >> 16));
    }
    float e[8][4];
#pragma unroll
    for (int g = 0; g < HH; ++g) {
        float pr[8];
#pragma unroll
        for (int h = 0; h < 8; ++h) pr[h] = pre[g * 8 + h];
        float z = 0.f;
#pragma unroll
        for (int q = 0; q < 4; ++q) {
            float m = 0.f;
#pragma unroll
            for (int h = 0; h < 8; ++h) m += pr[h] * vals[h][q];
            e[g][q] = __expf(m);
            z += e[g][q];
        }
#pragma unroll
        for (int o = 32; o; o >>= 1) z += __shfl_xor(z, o, 64);
        if (lane == 0) red[g][wave] = z;
    }
    __syncthreads();
#pragma unroll
    for (int g = 0; g < HH; ++g) {
        float rz = 1.f / (red[g][0] + red[g][1] + red[g][2] + red[g][3]);
#pragma unroll
        for (int q = 0; q < 4; ++q) e[g][q] *= rz;
    }
#pragma unroll
    for (int g = 0; g < HH; ++g) {
        float po[8];
#pragma unroll
        for (int h = 0; h < 8; ++h) po[h] = post[g * 8 + h];
        float o4[4];
#pragma unroll
        for (int q = 0; q < 4; ++q) {
            float s = 0.f;
#pragma unroll
            for (int h = 0; h < 8; ++h) s += po[h] * e[h][q];
            o4[q] = s;
        }
        uint2 w;
        w.x = pk2(o4[0], o4[1]);
        w.y = pk2(o4[2], o4[3]);
        *(uint2*)(a + ((size_t)(b * HH + g) * NN + i) * NN + 4 * tid) = w;
    }
}

// ---------------------------------------------------------------------------
// AV via MFMA, split-j into 2 f32 partials (summed in proj GEMM staging).
// Block: 4 waves x 16i = 64i, j-range 512. grid x = it(16)*2+js(2) = 32, y=16.
// 512 blocks -> 2 blocks/CU (8 waves/CU). Two independent MFMA acc chains
// (even/odd ks) double per-wave ILP; exact same summands.
// ---------------------------------------------------------------------------
__global__ __launch_bounds__(256) void av_mfma(
    const ushort* __restrict__ p, const ushort* __restrict__ qkv,
    float* __restrict__ opart) {
    __shared__ ushort Vs[16][520];
    int bx = blockIdx.x;
    int it = bx >> 1, js = bx & 1;
    int bh = blockIdx.y;
    int b = bh >> 3, h = bh & 7;
    int tid = threadIdx.x, wv = tid >> 6, l = tid & 63;
    int i0 = it * 64 + wv * 16;
    int j0 = js * 512;
    for (int jl = tid; jl < 512; jl += 256) {
        const ushort* src = qkv + (size_t)(b * NN + j0 + jl) * 384 + 256 + h * 16;
        short8 v0 = *(const short8*)src;
        short8 v1 = *(const short8*)(src + 8);
#pragma unroll
        for (int d = 0; d < 8; ++d) Vs[d][jl] = (ushort)v0[d];
#pragma unroll
        for (int d = 0; d < 8; ++d) Vs[8 + d][jl] = (ushort)v1[d];
    }
    __syncthreads();
    int lr = l & 15, lk = (l >> 4) * 8;
    const ushort* prow = p + ((size_t)bh * NN + i0 + lr) * NN + j0;
    f32x4 acc0 = {}, acc1 = {};
#pragma unroll
    for (int ks = 0; ks < 16; ks += 2) {
        int jb0 = ks * 32 + lk;
        int jb1 = (ks + 1) * 32 + lk;
        short8 bv0 = *(const short8*)&Vs[lr][jb0];
        short8 bv1 = *(const short8*)&Vs[lr][jb1];
        short8 a0 = *(const short8*)(prow + jb0);
        short8 a1 = *(const short8*)(prow + jb1);
        acc0 = __builtin_amdgcn_mfma_f32_16x16x32_bf16(a0, bv0, acc0, 0, 0, 0);
        acc1 = __builtin_amdgcn_mfma_f32_16x16x32_bf16(a1, bv1, acc1, 0, 0, 0);
    }
    f32x4 acc = acc0 + acc1;
#pragma unroll
    for (int q = 0; q < 4; ++q) {
        int m = i0 + (l >> 4) * 4 + q;
        opart[((size_t)js * MM + b * NN + m) * DD + h * 16 + lr] = acc[q];
    }
}

// ---------------------------------------------------------------------------
extern "C" void kernel_launch(void* const* d_in, const int* in_sizes, int n_in,
                              void* d_out, int out_size, void* d_ws, size_t ws_size,
                              hipStream_t stream) {
    const float* x         = (const float*)d_in[0];
    const float* dist      = (const float*)d_in[1];
    const float* attn_mask = (const float*)d_in[2];
    const float* local_mask= (const float*)d_in[3];
    const int*   edge_type = (const int*)d_in[4];
    const float* ln_g      = (const float*)d_in[5];
    const float* ln_b      = (const float*)d_in[6];
    const float* qkv_w     = (const float*)d_in[7];
    const float* proj_w    = (const float*)d_in[8];
    const float* proj_b    = (const float*)d_in[9];
    const float* th_pre    = (const float*)d_in[10];
    const float* th_post   = (const float*)d_in[11];
    const float* ls        = (const float*)d_in[12];
    const float* fc1_w     = (const float*)d_in[13];
    const float* fc1_b     = (const float*)d_in[14];
    const float* fc2_w     = (const float*)d_in[15];
    const float* fc2_b     = (const float*)d_in[16];
    const float* de_ln_g   = (const float*)d_in[17];
    const float* de_ln_b   = (const float*)d_in[18];
    const float* de_w      = (const float*)d_in[19];
    const float* de_b      = (const float*)d_in[20];
    const float* edge_emb  = (const float*)d_in[21];
    const float* rbf_mu    = (const float*)d_in[22];
    const float* rbf_sigma = (const float*)d_in[23];

    char* pws = (char*)d_ws;
    auto alloc = [&](size_t bytes) {
        char* r = pws;
        pws += (bytes + 255) & ~(size_t)255;
        return (void*)r;
    };
    const int NWQ = NL * 2 * 3 * DD * DD;
    const int NWP = NL * 2 * DD * DD;
    const int NW1 = NL * DHID * DD;
    const int NW2 = NL * DD * DHID;
    ushort* wq    = (ushort*)alloc((size_t)NWQ * 2);
    ushort* wp    = (ushort*)alloc((size_t)NWP * 2);
    ushort* w1    = (ushort*)alloc((size_t)NW1 * 2);
    ushort* w2    = (ushort*)alloc((size_t)NW2 * 2);
    ushort* abuf  = (ushort*)alloc((size_t)BB * HH * NN * NN * 2);  // 32 MB
    ushort* fmask = (ushort*)alloc((size_t)BB * NN * NN * 2);       // 4 MB
    ushort* amask = (ushort*)alloc((size_t)BB * NN * NN * 2);       // 4 MB
    float*  xbuf  = (float*)alloc((size_t)MM * DD * 4);
    ushort* qkvb  = (ushort*)alloc((size_t)MM * 3 * DD * 2);
    ushort* h1    = (ushort*)alloc((size_t)MM * DHID * 2);
    float*  opart = (float*)alloc((size_t)2 * MM * DD * 4);         // 2 MB
    float*  tab   = (float*)alloc((size_t)NL * 4 * TB * 8 * 4);     // 2 MB

    {
        int ntot = NWQ + NWP + NW1 + NW2;
        cvt4_kernel<<<(ntot + 255) / 256, 256, 0, stream>>>(
            qkv_w, NWQ, proj_w, NWP, fc1_w, NW1, fc2_w, NW2, wq, wp, w1, w2);
        maskprep_kernel<<<(BB * NN * NN + 255) / 256, 256, 0, stream>>>(
            attn_mask, local_mask, fmask, amask);
        table_kernel<<<(NL * 4 * TB + 255) / 256, 256, 0, stream>>>(
            de_ln_g, de_ln_b, de_w, de_b, edge_emb, rbf_mu, rbf_sigma, tab);
    }

    hipMemcpyAsync(xbuf, x, (size_t)MM * DD * 4, hipMemcpyDeviceToDevice, stream);

    for (int l = 0; l < NL; ++l) {
        const float* tabl = tab + (size_t)l * 4 * TB * 8;
        for (int inst = 0; inst < 2; ++inst) {
            gemm_mfma<1, GF_OUTBF, 128><<<dim3(MM / 64, 384 / 64), 256, 0, stream>>>(
                xbuf, wq + (size_t)(l * 2 + inst) * 3 * DD * DD,
                nullptr, nullptr, nullptr,
                ln_g + (l * 3 + inst) * DD, ln_b + (l * 3 + inst) * DD, qkvb, 384);
            score_mfma<<<dim3(NN / 64, NN / 16, BB), 256, 0, stream>>>(
                qkvb, dist, edge_type, tabl, inst == 0 ? fmask : amask, abuf);
            mixsm_kernel<<<BB * NN, 256, 0, stream>>>(
                abuf, th_pre + (l * 2 + inst) * HH * HH,
                th_post + (l * 2 + inst) * HH * HH);
            av_mfma<<<dim3(32, BB * HH), 256, 0, stream>>>(abuf, qkvb, opart);
            gemm_mfma<2, GF_BIAS | GF_RESID, 128>
                <<<dim3(MM / 64, DD / 64), 256, 0, stream>>>(
                opart, wp + (size_t)(l * 2 + inst) * DD * DD,
                proj_b + (l * 2 + inst) * DD, ls + (l * 3 + inst) * DD,
                xbuf, nullptr, nullptr, xbuf, DD);
        }

        gemm_mfma<1, GF_BIAS | GF_GELU | GF_OUTBF, 128>
            <<<dim3(MM / 64, DHID / 64), 256, 0, stream>>>(
            xbuf, w1 + (size_t)l * DHID * DD, fc1_b + l * DHID,
            nullptr, nullptr, ln_g + (l * 3 + 2) * DD, ln_b + (l * 3 + 2) * DD,
            h1, DHID);
        gemm_mfma<0, GF_BIAS | GF_RESID, 256>
            <<<dim3(MM / 64, DD / 64), 256, 0, stream>>>(
            h1, w2 + (size_t)l * DD * DHID, fc2_b + l * DD,
            ls + (l * 3 + 2) * DD, xbuf, nullptr, nullptr, xbuf, DD);
    }

    hipMemcpyAsync(d_out, xbuf, (size_t)MM * DD * 4, hipMemcpyDeviceToDevice, stream);
}

// Round 11
// 1314.834 us; speedup vs baseline: 1.1631x; 1.0845x over previous
//
#include <hip/hip_runtime.h>
#include <math.h>

#define BB 2
#define NN 1024
#define DD 128
#define HH 8
#define NL 8
#define RR 4
#define DHID 256
#define TWO_R 8
#define MM (BB*NN)
#define TB 2048   // bias table resolution over d in [0,20]

typedef __attribute__((ext_vector_type(8))) short short8;
typedef __attribute__((ext_vector_type(4))) float f32x4;

__device__ __forceinline__ float gelu_erf(float x) {
    return 0.5f * x * (1.0f + erff(x * 0.70710678118654752f));
}
// f32 -> bf16 round-to-nearest-even
__device__ __forceinline__ ushort f2b(float f) {
    union { float f; unsigned u; } v; v.f = f;
    return (ushort)((v.u + 0x7FFFu + ((v.u >> 16) & 1u)) >> 16);
}
__device__ __forceinline__ float b2f(ushort u) {
    union { unsigned u; float f; } v; v.u = ((unsigned)u) << 16;
    return v.f;
}
__device__ __forceinline__ unsigned pk2(float a, float b) {
    return ((unsigned)f2b(b) << 16) | (unsigned)f2b(a);
}

// ---------------------------------------------------------------------------
// Merged f32->bf16 weight conversion (4 segments, one elem/thread)
// ---------------------------------------------------------------------------
__global__ __launch_bounds__(256) void cvt4_kernel(
    const float* __restrict__ s0, int n0, const float* __restrict__ s1, int n1,
    const float* __restrict__ s2, int n2, const float* __restrict__ s3, int n3,
    ushort* __restrict__ d0, ushort* __restrict__ d1,
    ushort* __restrict__ d2, ushort* __restrict__ d3) {
    int t = blockIdx.x * 256 + threadIdx.x;
    if (t < n0) { d0[t] = f2b(s0[t]); return; } t -= n0;
    if (t < n1) { d1[t] = f2b(s1[t]); return; } t -= n1;
    if (t < n2) { d2[t] = f2b(s2[t]); return; } t -= n2;
    if (t < n3) { d3[t] = f2b(s3[t]); }
}

// masks -> bf16: fmask = attn+local, amask = attn
__global__ __launch_bounds__(256) void maskprep_kernel(
    const float* __restrict__ am, const float* __restrict__ lm,
    ushort* __restrict__ fmask, ushort* __restrict__ amask) {
    int t = blockIdx.x * 256 + threadIdx.x;
    if (t >= BB * NN * NN) return;
    float a = am[t];
    amask[t] = f2b(a);
    fmask[t] = f2b(a + lm[t]);
}

// ---------------------------------------------------------------------------
// Bias table: tab[l][et][idx][h] = gelu(LN([rbf(d_idx), emb_l[et]]) @ W_l + b_l)
// ---------------------------------------------------------------------------
__global__ __launch_bounds__(256) void table_kernel(
    const float* __restrict__ de_ln_g, const float* __restrict__ de_ln_b,
    const float* __restrict__ de_w, const float* __restrict__ de_b,
    const float* __restrict__ edge_emb, const float* __restrict__ mu,
    const float* __restrict__ sigma, float* __restrict__ tab) {
    int t = blockIdx.x * 256 + threadIdx.x;
    if (t >= NL * 4 * TB) return;
    int idx = t & (TB - 1);
    int et = (t >> 11) & 3;
    int l = t >> 13;
    float d = idx * (20.0f / (float)(TB - 1));
    float f[8];
#pragma unroll
    for (int r = 0; r < RR; ++r) {
        float u = (d - mu[r]) / sigma[r];
        f[r] = expf(-u * u);
    }
#pragma unroll
    for (int r = 0; r < RR; ++r) f[4 + r] = edge_emb[(l * 4 + et) * RR + r];
    float m = 0.f;
#pragma unroll
    for (int r = 0; r < 8; ++r) m += f[r];
    m *= 0.125f;
    float v = 0.f;
#pragma unroll
    for (int r = 0; r < 8; ++r) { float dd = f[r] - m; v += dd * dd; }
    v *= 0.125f;
    float inv = rsqrtf(v + 1e-5f);
    float fn[8];
#pragma unroll
    for (int r = 0; r < 8; ++r)
        fn[r] = (f[r] - m) * inv * de_ln_g[l * 8 + r] + de_ln_b[l * 8 + r];
#pragma unroll
    for (int h = 0; h < HH; ++h) {
        float z = de_b[l * 8 + h];
#pragma unroll
        for (int r = 0; r < 8; ++r) z += de_w[(l * 8 + h) * 8 + r] * fn[r];
        tab[(size_t)t * 8 + h] = gelu_erf(z);
    }
}

// ---------------------------------------------------------------------------
// Per-layer bias materialization, POINT-MAJOR [b][i][j][8h] bf16 (uint4/point).
// Fully coalesced: dist/et reads streaming, one uint4 store per thread.
// ---------------------------------------------------------------------------
__global__ __launch_bounds__(256) void biasp_kernel(
    const float* __restrict__ dist, const int* __restrict__ edge_type,
    const float* __restrict__ tabl, ushort* __restrict__ biasp) {
    int t = blockIdx.x * 256 + threadIdx.x;
    if (t >= BB * NN * NN) return;
    float d = dist[t];
    int et = edge_type[t];
    float u = d * ((float)(TB - 1) / 20.0f);
    int t0i = (int)u;
    t0i = t0i < 0 ? 0 : (t0i > TB - 2 ? TB - 2 : t0i);
    float fr = u - (float)t0i;
    const float* tp = tabl + ((size_t)et * TB + t0i) * 8;
    float4 lo0 = *(const float4*)tp;
    float4 lo1 = *(const float4*)(tp + 4);
    float4 hi0 = *(const float4*)(tp + 8);
    float4 hi1 = *(const float4*)(tp + 12);
    uint4 w;
    w.x = pk2(lo0.x + fr * (hi0.x - lo0.x), lo0.y + fr * (hi0.y - lo0.y));
    w.y = pk2(lo0.z + fr * (hi0.z - lo0.z), lo0.w + fr * (hi0.w - lo0.w));
    w.z = pk2(lo1.x + fr * (hi1.x - lo1.x), lo1.y + fr * (hi1.y - lo1.y));
    w.w = pk2(lo1.z + fr * (hi1.z - lo1.z), lo1.w + fr * (hi1.w - lo1.w));
    *reinterpret_cast<uint4*>(biasp + (size_t)t * 8) = w;
}

// ---------------------------------------------------------------------------
// MFMA GEMM: unchanged from R7.
// ---------------------------------------------------------------------------
#define GF_BIAS 1
#define GF_GELU 2
#define GF_RESID 4
#define GF_OUTBF 8

template <int AMODE, int FLAGS, int KDIM>
__global__ __launch_bounds__(256) void gemm_mfma(
    const void* __restrict__ Ain, const ushort* __restrict__ W,
    const float* __restrict__ bias, const float* __restrict__ ls,
    const float* __restrict__ resid, const float* __restrict__ lng,
    const float* __restrict__ lnb, void* __restrict__ out, int Nd) {
    __shared__ ushort As[64][KDIM + 8];
    __shared__ ushort Ws[64][KDIM + 8];
    int tid = threadIdx.x;
    int bm = blockIdx.x, bn = blockIdx.y;
    if (AMODE == 1) {
        int r = tid >> 2, c = tid & 3;
        const float* xr = (const float*)Ain + (size_t)(bm * 64 + r) * 128 + c * 32;
        float v[32];
        float s = 0.f, ss = 0.f;
#pragma unroll
        for (int k = 0; k < 8; ++k) {
            float4 f = ((const float4*)xr)[k];
            v[4 * k] = f.x; v[4 * k + 1] = f.y; v[4 * k + 2] = f.z; v[4 * k + 3] = f.w;
            s += f.x + f.y + f.z + f.w;
            ss += f.x * f.x + f.y * f.y + f.z * f.z + f.w * f.w;
        }
        s += __shfl_xor(s, 1, 64);  s += __shfl_xor(s, 2, 64);
        ss += __shfl_xor(ss, 1, 64); ss += __shfl_xor(ss, 2, 64);
        float mean = s * (1.f / 128.f);
        float var = ss * (1.f / 128.f) - mean * mean;
        float inv = rsqrtf(var + 1e-5f);
        unsigned* dst = (unsigned*)&As[r][c * 32];
#pragma unroll
        for (int k = 0; k < 16; ++k) {
            int col = c * 32 + 2 * k;
            float a0 = (v[2 * k] - mean) * inv * lng[col] + lnb[col];
            float a1 = (v[2 * k + 1] - mean) * inv * lng[col + 1] + lnb[col + 1];
            dst[k] = pk2(a0, a1);
        }
    } else if (AMODE == 2) {
        const float* Apart = (const float*)Ain;
        for (int v = tid; v < 64 * 32; v += 256) {
            int r = v >> 5, c = v & 31;
            size_t off = (size_t)(bm * 64 + r) * 128 + c * 4;
            float4 s0 = *(const float4*)(Apart + off);
            float4 s1 = *(const float4*)(Apart + (size_t)MM * 128 + off);
            unsigned* dst = (unsigned*)&As[r][c * 4];
            dst[0] = pk2(s0.x + s1.x, s0.y + s1.y);
            dst[1] = pk2(s0.z + s1.z, s0.w + s1.w);
        }
    } else {
        const ushort* A = (const ushort*)Ain;
        for (int v = tid; v < 64 * KDIM / 8; v += 256) {
            int r = v / (KDIM / 8), c = v % (KDIM / 8);
            *(short8*)&As[r][c * 8] =
                *(const short8*)(A + (size_t)(bm * 64 + r) * KDIM + c * 8);
        }
    }
    for (int v = tid; v < 64 * KDIM / 8; v += 256) {
        int r = v / (KDIM / 8), c = v % (KDIM / 8);
        *(short8*)&Ws[r][c * 8] =
            *(const short8*)(W + (size_t)(bn * 64 + r) * KDIM + c * 8);
    }
    __syncthreads();
    int wv = tid >> 6, l = tid & 63;
    int wm = (wv >> 1) * 32, wn = (wv & 1) * 32;
    int lr = l & 15, lk = (l >> 4) * 8;
    f32x4 acc[2][2] = {};
#pragma unroll
    for (int k0 = 0; k0 < KDIM; k0 += 32) {
        short8 af[2], bf[2];
        af[0] = *(const short8*)&As[wm + lr][k0 + lk];
        af[1] = *(const short8*)&As[wm + 16 + lr][k0 + lk];
        bf[0] = *(const short8*)&Ws[wn + lr][k0 + lk];
        bf[1] = *(const short8*)&Ws[wn + 16 + lr][k0 + lk];
#pragma unroll
        for (int mf = 0; mf < 2; ++mf)
#pragma unroll
            for (int nf = 0; nf < 2; ++nf)
                acc[mf][nf] = __builtin_amdgcn_mfma_f32_16x16x32_bf16(
                    af[mf], bf[nf], acc[mf][nf], 0, 0, 0);
    }
#pragma unroll
    for (int mf = 0; mf < 2; ++mf)
#pragma unroll
        for (int nf = 0; nf < 2; ++nf) {
            int n = bn * 64 + wn + nf * 16 + lr;
            float bv = (FLAGS & GF_BIAS) ? bias[n] : 0.f;
            float lv = (FLAGS & GF_RESID) ? ls[n] : 0.f;
#pragma unroll
            for (int q = 0; q < 4; ++q) {
                int m = bm * 64 + wm + mf * 16 + (l >> 4) * 4 + q;
                float c = acc[mf][nf][q];
                c += bv;
                if (FLAGS & GF_GELU) c = gelu_erf(c);
                size_t idx = (size_t)m * Nd + n;
                if (FLAGS & GF_RESID) c = resid[idx] + lv * c;
                if (FLAGS & GF_OUTBF) ((ushort*)out)[idx] = f2b(c);
                else ((float*)out)[idx] = c;
            }
        }
}

// ---------------------------------------------------------------------------
// Score v3 (R10): ALL loads coalesced.
//  - Q tile (16x128) + K tile (64x128) staged in LDS via 16B chunk loads
//    (wave = 4x256B segments, 16 lines/instr vs 64-line lane-scatter before);
//    MFMA fragments read from LDS.
//  - bias read point-major (uint4/point, coalesced) from biasp; + mask -> bm2.
//  - K-tile LDS unioned with score-staging st (disjoint phases, 3 barriers).
//  - coalesced b128 writeout.
// grid: (jt=16, it=64, b=2); block 16i x 64j, all 8 heads (wave w: heads 2w,2w+1).
// ---------------------------------------------------------------------------
__global__ __launch_bounds__(256) void score_mfma(
    const ushort* __restrict__ qkv, const ushort* __restrict__ biasp,
    const ushort* __restrict__ mask, ushort* __restrict__ a) {
    __shared__ ushort Qs[16][136];      // 4.25 KB
    __shared__ ushort kst[9216];        // ph2: K[64][136] (8704); ph3/4: st[8][16][72] (9216)
    __shared__ unsigned bm2[4][1024];   // 16 KB
    int tid = threadIdx.x, wv = tid >> 6, l = tid & 63;
    int jt = blockIdx.x, it = blockIdx.y, b = blockIdx.z;
    int i0 = it * 16, j0 = jt * 64;
    // ---- phase 0a: stage Q tile (coalesced 16B chunks, 1/thread) ----
    {
        int r = tid >> 4, c = tid & 15;
        *(short8*)&Qs[r][c * 8] =
            *(const short8*)(qkv + (size_t)(b * NN + i0 + r) * 384 + c * 8);
    }
    // ---- phase 0b: stage K tile (coalesced, 4/thread) ----
#pragma unroll
    for (int p = 0; p < 4; ++p) {
        int cidx = p * 256 + tid;
        int r = cidx >> 4, c = cidx & 15;
        *(short8*)&kst[r * 136 + c * 8] =
            *(const short8*)(qkv + (size_t)(b * NN + j0 + r) * 384 + 128 + c * 8);
    }
    // ---- phase 0c: bm2 = mask + bias (4 consecutive points/thread, coalesced) ----
    {
        int p0 = tid * 4;
        size_t mi = ((size_t)(b * NN + i0 + (p0 >> 6))) * NN + j0 + (p0 & 63);
        uint2 mk = *(const uint2*)(mask + mi);
        float mk4[4] = { b2f((ushort)(mk.x & 0xFFFF)), b2f((ushort)(mk.x >> 16)),
                         b2f((ushort)(mk.y & 0xFFFF)), b2f((ushort)(mk.y >> 16)) };
        unsigned o[4][4];
#pragma unroll
        for (int p = 0; p < 4; ++p) {
            uint4 bp = *reinterpret_cast<const uint4*>(biasp + (mi + p) * 8);
            float m = mk4[p];
            unsigned wds[4] = { bp.x, bp.y, bp.z, bp.w };
#pragma unroll
            for (int hp = 0; hp < 4; ++hp)
                o[p][hp] = pk2(b2f((ushort)(wds[hp] & 0xFFFF)) + m,
                               b2f((ushort)(wds[hp] >> 16)) + m);
        }
#pragma unroll
        for (int hp = 0; hp < 4; ++hp) {
            uint4 w4;
            w4.x = o[0][hp]; w4.y = o[1][hp]; w4.z = o[2][hp]; w4.w = o[3][hp];
            *reinterpret_cast<uint4*>(&bm2[hp][p0]) = w4;
        }
    }
    __syncthreads();
    // ---- phase 2: fragments from LDS + QK^T MFMAs ----
    int h0 = wv * 2;
    int lr = l & 15, kk = (l >> 4) * 8;
    short8 zero = {0, 0, 0, 0, 0, 0, 0, 0};
    bool lo = kk < 16;
    short8 af[2];
    short8 bf[2][4];
    f32x4 acc[2][4] = {};
#pragma unroll
    for (int hh = 0; hh < 2; ++hh) {
        af[hh] = zero;
        if (lo) af[hh] = *(const short8*)&Qs[lr][(h0 + hh) * 16 + kk];
#pragma unroll
        for (int nf = 0; nf < 4; ++nf) {
            bf[hh][nf] = zero;
            if (lo) bf[hh][nf] =
                *(const short8*)&kst[(nf * 16 + lr) * 136 + (h0 + hh) * 16 + kk];
        }
    }
#pragma unroll
    for (int hh = 0; hh < 2; ++hh)
#pragma unroll
        for (int nf = 0; nf < 4; ++nf)
            acc[hh][nf] = __builtin_amdgcn_mfma_f32_16x16x32_bf16(
                af[hh], bf[hh][nf], acc[hh][nf], 0, 0, 0);
    __syncthreads();   // all K-tile reads done; kst becomes st
    // ---- phase 3: add mask+bias, stage score tile (st aliases kst) ----
#pragma unroll
    for (int nf = 0; nf < 4; ++nf)
#pragma unroll
        for (int q = 0; q < 4; ++q) {
            int il = (l >> 4) * 4 + q;
            int jl = nf * 16 + lr;
            unsigned bmv = bm2[wv][il * 64 + jl];
            kst[(h0 * 16 + il) * 72 + jl] =
                f2b(acc[0][nf][q] * 0.25f + b2f((ushort)(bmv & 0xFFFF)));
            kst[((h0 + 1) * 16 + il) * 72 + jl] =
                f2b(acc[1][nf][q] * 0.25f + b2f((ushort)(bmv >> 16)));
        }
    __syncthreads();
    // ---- phase 4: coalesced writeout ----
    {
        int row = tid >> 1;
        int h = row >> 4, il = row & 15;
        int jl = (tid & 1) * 32;
        const ushort* src = &kst[(h * 16 + il) * 72 + jl];
        ushort* dst = a + ((size_t)(b * HH + h) * NN + i0 + il) * NN + j0 + jl;
        *reinterpret_cast<uint4*>(dst)      = *reinterpret_cast<const uint4*>(src);
        *reinterpret_cast<uint4*>(dst + 8)  = *reinterpret_cast<const uint4*>(src + 8);
        *reinterpret_cast<uint4*>(dst + 16) = *reinterpret_cast<const uint4*>(src + 16);
        *reinterpret_cast<uint4*>(dst + 24) = *reinterpret_cast<const uint4*>(src + 24);
    }
}

// ---------------------------------------------------------------------------
// Talking-heads: unchanged from R7.
// ---------------------------------------------------------------------------
__global__ __launch_bounds__(256) void mixsm_kernel(
    ushort* __restrict__ a, const float* __restrict__ pre,
    const float* __restrict__ post) {
    __shared__ float red[8][4];
    int bi = blockIdx.x;
    int b = bi >> 10, i = bi & 1023;
    int tid = threadIdx.x, wave = tid >> 6, lane = tid & 63;
    float vals[8][4];
#pragma unroll
    for (int h = 0; h < HH; ++h) {
        uint2 w = *(const uint2*)(a + ((size_t)(b * HH + h) * NN + i) * NN + 4 * tid);
        vals[h][0] = b2f((ushort)(w.x & 0xFFFF));
        vals[h][1] = b2f((ushort)(w.x >> 16));
        vals[h][2] = b2f((ushort)(w.y & 0xFFFF));
        vals[h][3] = b2f((ushort)(w.y >> 16));
    }
    float e[8][4];
#pragma unroll
    for (int g = 0; g < HH; ++g) {
        float pr[8];
#pragma unroll
        for (int h = 0; h < 8; ++h) pr[h] = pre[g * 8 + h];
        float z = 0.f;
#pragma unroll
        for (int q = 0; q < 4; ++q) {
            float m = 0.f;
#pragma unroll
            for (int h = 0; h < 8; ++h) m += pr[h] * vals[h][q];
            e[g][q] = __expf(m);
            z += e[g][q];
        }
#pragma unroll
        for (int o = 32; o; o >>= 1) z += __shfl_xor(z, o, 64);
        if (lane == 0) red[g][wave] = z;
    }
    __syncthreads();
#pragma unroll
    for (int g = 0; g < HH; ++g) {
        float rz = 1.f / (red[g][0] + red[g][1] + red[g][2] + red[g][3]);
#pragma unroll
        for (int q = 0; q < 4; ++q) e[g][q] *= rz;
    }
#pragma unroll
    for (int g = 0; g < HH; ++g) {
        float po[8];
#pragma unroll
        for (int h = 0; h < 8; ++h) po[h] = post[g * 8 + h];
        float o4[4];
#pragma unroll
        for (int q = 0; q < 4; ++q) {
            float s = 0.f;
#pragma unroll
            for (int h = 0; h < 8; ++h) s += po[h] * e[h][q];
            o4[q] = s;
        }
        uint2 w;
        w.x = pk2(o4[0], o4[1]);
        w.y = pk2(o4[2], o4[3]);
        *(uint2*)(a + ((size_t)(b * HH + g) * NN + i) * NN + 4 * tid) = w;
    }
}

// ---------------------------------------------------------------------------
// AV via MFMA: unchanged from R8.
// ---------------------------------------------------------------------------
__global__ __launch_bounds__(256) void av_mfma(
    const ushort* __restrict__ p, const ushort* __restrict__ qkv,
    float* __restrict__ opart) {
    __shared__ ushort Vs[16][520];
    int bx = blockIdx.x;
    int it = bx >> 1, js = bx & 1;
    int bh = blockIdx.y;
    int b = bh >> 3, h = bh & 7;
    int tid = threadIdx.x, wv = tid >> 6, l = tid & 63;
    int i0 = it * 64 + wv * 16;
    int j0 = js * 512;
    for (int jl = tid; jl < 512; jl += 256) {
        const ushort* src = qkv + (size_t)(b * NN + j0 + jl) * 384 + 256 + h * 16;
        short8 v0 = *(const short8*)src;
        short8 v1 = *(const short8*)(src + 8);
#pragma unroll
        for (int d = 0; d < 8; ++d) Vs[d][jl] = (ushort)v0[d];
#pragma unroll
        for (int d = 0; d < 8; ++d) Vs[8 + d][jl] = (ushort)v1[d];
    }
    __syncthreads();
    int lr = l & 15, lk = (l >> 4) * 8;
    const ushort* prow = p + ((size_t)bh * NN + i0 + lr) * NN + j0;
    f32x4 acc0 = {}, acc1 = {};
#pragma unroll
    for (int ks = 0; ks < 16; ks += 2) {
        int jb0 = ks * 32 + lk;
        int jb1 = (ks + 1) * 32 + lk;
        short8 bv0 = *(const short8*)&Vs[lr][jb0];
        short8 bv1 = *(const short8*)&Vs[lr][jb1];
        short8 a0 = *(const short8*)(prow + jb0);
        short8 a1 = *(const short8*)(prow + jb1);
        acc0 = __builtin_amdgcn_mfma_f32_16x16x32_bf16(a0, bv0, acc0, 0, 0, 0);
        acc1 = __builtin_amdgcn_mfma_f32_16x16x32_bf16(a1, bv1, acc1, 0, 0, 0);
    }
    f32x4 acc = acc0 + acc1;
#pragma unroll
    for (int q = 0; q < 4; ++q) {
        int m = i0 + (l >> 4) * 4 + q;
        opart[((size_t)js * MM + b * NN + m) * DD + h * 16 + lr] = acc[q];
    }
}

// ---------------------------------------------------------------------------
extern "C" void kernel_launch(void* const* d_in, const int* in_sizes, int n_in,
                              void* d_out, int out_size, void* d_ws, size_t ws_size,
                              hipStream_t stream) {
    const float* x         = (const float*)d_in[0];
    const float* dist      = (const float*)d_in[1];
    const float* attn_mask = (const float*)d_in[2];
    const float* local_mask= (const float*)d_in[3];
    const int*   edge_type = (const int*)d_in[4];
    const float* ln_g      = (const float*)d_in[5];
    const float* ln_b      = (const float*)d_in[6];
    const float* qkv_w     = (const float*)d_in[7];
    const float* proj_w    = (const float*)d_in[8];
    const float* proj_b    = (const float*)d_in[9];
    const float* th_pre    = (const float*)d_in[10];
    const float* th_post   = (const float*)d_in[11];
    const float* ls        = (const float*)d_in[12];
    const float* fc1_w     = (const float*)d_in[13];
    const float* fc1_b     = (const float*)d_in[14];
    const float* fc2_w     = (const float*)d_in[15];
    const float* fc2_b     = (const float*)d_in[16];
    const float* de_ln_g   = (const float*)d_in[17];
    const float* de_ln_b   = (const float*)d_in[18];
    const float* de_w      = (const float*)d_in[19];
    const float* de_b      = (const float*)d_in[20];
    const float* edge_emb  = (const float*)d_in[21];
    const float* rbf_mu    = (const float*)d_in[22];
    const float* rbf_sigma = (const float*)d_in[23];

    char* pws = (char*)d_ws;
    auto alloc = [&](size_t bytes) {
        char* r = pws;
        pws += (bytes + 255) & ~(size_t)255;
        return (void*)r;
    };
    const int NWQ = NL * 2 * 3 * DD * DD;
    const int NWP = NL * 2 * DD * DD;
    const int NW1 = NL * DHID * DD;
    const int NW2 = NL * DD * DHID;
    ushort* wq    = (ushort*)alloc((size_t)NWQ * 2);
    ushort* wp    = (ushort*)alloc((size_t)NWP * 2);
    ushort* w1    = (ushort*)alloc((size_t)NW1 * 2);
    ushort* w2    = (ushort*)alloc((size_t)NW2 * 2);
    ushort* abuf  = (ushort*)alloc((size_t)BB * HH * NN * NN * 2);  // 32 MB
    ushort* biasp = (ushort*)alloc((size_t)BB * NN * NN * HH * 2);  // 32 MB point-major
    ushort* fmask = (ushort*)alloc((size_t)BB * NN * NN * 2);       // 4 MB
    ushort* amask = (ushort*)alloc((size_t)BB * NN * NN * 2);       // 4 MB
    float*  xbuf  = (float*)alloc((size_t)MM * DD * 4);
    ushort* qkvb  = (ushort*)alloc((size_t)MM * 3 * DD * 2);
    ushort* h1    = (ushort*)alloc((size_t)MM * DHID * 2);
    float*  opart = (float*)alloc((size_t)2 * MM * DD * 4);         // 2 MB
    float*  tab   = (float*)alloc((size_t)NL * 4 * TB * 8 * 4);     // 2 MB

    {
        int ntot = NWQ + NWP + NW1 + NW2;
        cvt4_kernel<<<(ntot + 255) / 256, 256, 0, stream>>>(
            qkv_w, NWQ, proj_w, NWP, fc1_w, NW1, fc2_w, NW2, wq, wp, w1, w2);
        maskprep_kernel<<<(BB * NN * NN + 255) / 256, 256, 0, stream>>>(
            attn_mask, local_mask, fmask, amask);
        table_kernel<<<(NL * 4 * TB + 255) / 256, 256, 0, stream>>>(
            de_ln_g, de_ln_b, de_w, de_b, edge_emb, rbf_mu, rbf_sigma, tab);
    }

    hipMemcpyAsync(xbuf, x, (size_t)MM * DD * 4, hipMemcpyDeviceToDevice, stream);

    for (int l = 0; l < NL; ++l) {
        const float* tabl = tab + (size_t)l * 4 * TB * 8;
        biasp_kernel<<<(BB * NN * NN + 255) / 256, 256, 0, stream>>>(
            dist, edge_type, tabl, biasp);
        for (int inst = 0; inst < 2; ++inst) {
            gemm_mfma<1, GF_OUTBF, 128><<<dim3(MM / 64, 384 / 64), 256, 0, stream>>>(
                xbuf, wq + (size_t)(l * 2 + inst) * 3 * DD * DD,
                nullptr, nullptr, nullptr,
                ln_g + (l * 3 + inst) * DD, ln_b + (l * 3 + inst) * DD, qkvb, 384);
            score_mfma<<<dim3(NN / 64, NN / 16, BB), 256, 0, stream>>>(
                qkvb, biasp, inst == 0 ? fmask : amask, abuf);
            mixsm_kernel<<<BB * NN, 256, 0, stream>>>(
                abuf, th_pre + (l * 2 + inst) * HH * HH,
                th_post + (l * 2 + inst) * HH * HH);
            av_mfma<<<dim3(32, BB * HH), 256, 0, stream>>>(abuf, qkvb, opart);
            gemm_mfma<2, GF_BIAS | GF_RESID, 128>
                <<<dim3(MM / 64, DD / 64), 256, 0, stream>>>(
                opart, wp + (size_t)(l * 2 + inst) * DD * DD,
                proj_b + (l * 2 + inst) * DD, ls + (l * 3 + inst) * DD,
                xbuf, nullptr, nullptr, xbuf, DD);
        }

        gemm_mfma<1, GF_BIAS | GF_GELU | GF_OUTBF, 128>
            <<<dim3(MM / 64, DHID / 64), 256, 0, stream>>>(
            xbuf, w1 + (size_t)l * DHID * DD, fc1_b + l * DHID,
            nullptr, nullptr, ln_g + (l * 3 + 2) * DD, ln_b + (l * 3 + 2) * DD,
            h1, DHID);
        gemm_mfma<0, GF_BIAS | GF_RESID, 256>
            <<<dim3(MM / 64, DD / 64), 256, 0, stream>>>(
            h1, w2 + (size_t)l * DD * DHID, fc2_b + l * DD,
            ls + (l * 3 + 2) * DD, xbuf, nullptr, nullptr, xbuf, DD);
    }

    hipMemcpyAsync(d_out, xbuf, (size_t)MM * DD * 4, hipMemcpyDeviceToDevice, stream);
}